// Round 3
// baseline (254.958 us; speedup 1.0000x reference)
//
#include <hip/hip_runtime.h>
#include <math.h>

#define NSITE 100
#define NOCC  50
#define DIM   128
#define KDET  4
#define NTAB  400                         // K*(N_UP+N_DOWN)
#define TP_FLOATS ((4 + 144) * NTAB)      // T then P' in ws

// ---------------------------------------------------------------------------
// R18: GEMM collapsed into T[4][400]/P'[144][400] table adds.
// R19: pipelined pivot + SALU parity: 197 -> 170us. VGPR_Count=36 => 50 q's
//      were spill/AGPR-shuttled (WRITE_SIZE 13.5MB of scratch).
// R20: waves_per_eu(6) didn't fix it: VGPR 40, spills remain (3.3MB), det
//      got WORSE (181us, occupancy -5). Conclusion: 50 live named regs per
//      wave will always spill; restructure instead of fighting the RA.
// R21 (this round): 2 waves per determinant, 25 columns each (column c
//      owned by wave half c&1). Owner of step J publishes {mult,p,pivbits}
//      via LDS; 1 barrier/step (double-buffered by parity); both halves
//      apply the rank-1 update to their 25 cols. Live state: 25 q + ~20
//      transients -> no spills, 8 waves/EU cap, per-wave VALU halved.
//      Update rule "local reg L >= J>>1" is half-uniform; boundary extras
//      only touch dead columns (masked mult) -> live math bit-identical.
// ---------------------------------------------------------------------------

// Wave64 max-reduction via DPP (VALU-only). Lane 63 ends with global max.
__device__ __forceinline__ unsigned dpp_max64_to_lane63(unsigned x) {
  unsigned t;
  t = (unsigned)__builtin_amdgcn_update_dpp((int)x, (int)x, 0x111, 0xf, 0xf, false);
  x = x > t ? x : t;
  t = (unsigned)__builtin_amdgcn_update_dpp((int)x, (int)x, 0x112, 0xf, 0xf, false);
  x = x > t ? x : t;
  t = (unsigned)__builtin_amdgcn_update_dpp((int)x, (int)x, 0x114, 0xf, 0xf, false);
  x = x > t ? x : t;
  t = (unsigned)__builtin_amdgcn_update_dpp((int)x, (int)x, 0x118, 0xf, 0xf, false);
  x = x > t ? x : t;
  t = (unsigned)__builtin_amdgcn_update_dpp((int)x, (int)x, 0x142, 0xa, 0xf, false);
  x = x > t ? x : t;
  t = (unsigned)__builtin_amdgcn_update_dpp((int)x, (int)x, 0x143, 0xc, 0xf, false);
  x = x > t ? x : t;
  return x;
}

// 25 local column registers
#define REPC(X) X(0) X(1) X(2) X(3) X(4) X(5) X(6) X(7) X(8) X(9) \
  X(10) X(11) X(12) X(13) X(14) X(15) X(16) X(17) X(18) X(19) \
  X(20) X(21) X(22) X(23) X(24)

// ---- Precompute: T[c][j] = tok[c].W_j ; P'[s][j] = pos[s].W_j + b_j ------
__global__ __launch_bounds__(256) void tp_kernel(
    const float* __restrict__ tok, const float* __restrict__ pos,
    const float* __restrict__ W,   const float* __restrict__ bvec,
    float* __restrict__ T, float* __restrict__ P)
{
  const int gid = blockIdx.x * 256 + threadIdx.x;
  if (gid >= 148 * NTAB) return;
  const int row = gid / NTAB;
  const int col = gid - row * NTAB;
  const float4* h4 = (const float4*)((row < 4) ? (tok + (size_t)row * DIM)
                                               : (pos + (size_t)(row - 4) * DIM));
  const float4* w4 = (const float4*)(W + (size_t)col * DIM);
  float acc = 0.0f;
  #pragma unroll
  for (int i = 0; i < DIM / 4; ++i) {
    float4 a = h4[i], b = w4[i];
    acc = fmaf(a.x, b.x, acc);
    acc = fmaf(a.y, b.y, acc);
    acc = fmaf(a.z, b.z, acc);
    acc = fmaf(a.w, b.w, acc);
  }
  if (row < 4) T[(size_t)row * NTAB + col] = acc;
  else         P[(size_t)(row - 4) * NTAB + col] = acc + bvec[col];
}

// Block = 256 threads = 4 waves = 2 determinants (each det: 2 waves).
// Grid (B, spin, detpair). Wave w: dloc = w>>1 (det in block), h = w&1
// (column half). Lane r owns row r; local reg L holds column 2L+h of det
// k = blockIdx.z*2 + dloc.
__global__ __launch_bounds__(256)
__attribute__((amdgpu_waves_per_eu(8)))
void det_kernel(
    const int*   __restrict__ configs,   // (B,100) int32
    const float* __restrict__ T,         // (4,400)
    const float* __restrict__ P,         // (144,400)  includes bias
    double*      __restrict__ dets)      // (B,2,4,2)  {logdet, sign}
{
  const int b    = blockIdx.x;
  const int spin = blockIdx.y;

  __shared__ int cfg[NSITE];
  __shared__ int idx[NOCC];
  __shared__ unsigned long long omask[2];
  __shared__ float mbuf[2][2][64];   // [slot parity][det][lane] multipliers
  __shared__ int   meta[2][2][2];    // [slot parity][det][{p, piv_bits}]

  const int tid = threadIdx.x;

  // ---- wave-parallel occupied-index build (ballot + prefix popcount) ----
  // semantics == reference argsort(-mask)[:50] then sort: all occupied
  // sites ascending (capped 50) + smallest unoccupied fills, merged sorted.
  bool occv = false;
  if (tid < NSITE) {
    const int c = configs[(size_t)b * NSITE + tid];
    cfg[tid] = c;
    occv = (spin == 0) ? (c == 1 || c == 3) : (c == 2 || c == 3);
  }
  const unsigned long long bal = __ballot(occv);
  if ((tid & 63) == 0 && tid < 128) omask[tid >> 6] = bal;
  __syncthreads();
  if (tid < NSITE) {
    const unsigned long long m0 = omask[0], m1 = omask[1];
    const int mtot = __popcll(m0) + __popcll(m1);
    const int need = (mtot < NOCC) ? (NOCC - mtot) : 0;
    int pocc;
    if (tid >= 64) pocc = __popcll(m0) + __popcll(m1 & ((1ull << (tid - 64)) - 1ull));
    else           pocc = __popcll(m0 & ((1ull << tid) - 1ull));
    const int punocc = tid - pocc;
    const bool sel = occv ? (pocc < NOCC) : (punocc < need);
    const int  poscap = (pocc  < NOCC) ? pocc  : NOCC;
    const int  pfill  = (punocc < need) ? punocc : need;
    if (sel) idx[poscap + pfill] = tid;
  }
  __syncthreads();

  const int lane  = tid & 63;
  const int wave  = tid >> 6;
  const int dloc  = __builtin_amdgcn_readfirstlane(wave >> 1);  // det in block
  const int h     = __builtin_amdgcn_readfirstlane(wave & 1);   // column half
  const int k     = blockIdx.z * 2 + dloc;                      // det index
  const int colbase = spin * 200 + k * 50;                      // uniform

  const bool act  = (lane < NOCC);
  const int  site = idx[act ? lane : 0];
  const int  cc0  = cfg[site];
  // this wave's columns: colbase + 2L + h, L = 0..24 (stride-2 scalar loads)
  const float* Trow = T + (size_t)cc0  * NTAB + colbase + h;
  const float* Prow = P + (size_t)site * NTAB + colbase + h;

  #define DECLQ(i) float q##i;
  REPC(DECLQ)
  #undef DECLQ
  #define LQ(i) q##i = Trow[2 * (i)] + Prow[2 * (i)];
  REPC(LQ)
  #undef LQ

  // zero inactive lanes so they never win the pivot and updates stay benign
  #define ZEROQ(i) q##i = act ? q##i : 0.0f;
  REPC(ZEROQ)
  #undef ZEROQ

  // ---- cooperative LU with implicit partial pivoting --------------------
  unsigned aliveq = act ? 0xFFFFFFFFu : 0u;   // per-lane alive mask
  float    mant_prod = 1.0f;                  // pivot mantissa product < 2^50
  int      esum = 0;
  unsigned sgnx = 0u;
  unsigned long long chosen = 0ull;
  int      invsum = 0;
  const unsigned lu = (unsigned)lane;

  // single rank-1 update of local reg L: q_L -= mult * q_L[pivot lane]
  #define UPD(L) { const float pc = __int_as_float( \
      __builtin_amdgcn_readlane(__float_as_int(q##L), p)); \
      q##L = fmaf(-mult, pc, q##L); }

  #define UPDFROM_24 UPD(24)
  #define UPDFROM_23 UPD(23) UPDFROM_24
  #define UPDFROM_22 UPD(22) UPDFROM_23
  #define UPDFROM_21 UPD(21) UPDFROM_22
  #define UPDFROM_20 UPD(20) UPDFROM_21
  #define UPDFROM_19 UPD(19) UPDFROM_20
  #define UPDFROM_18 UPD(18) UPDFROM_19
  #define UPDFROM_17 UPD(17) UPDFROM_18
  #define UPDFROM_16 UPD(16) UPDFROM_17
  #define UPDFROM_15 UPD(15) UPDFROM_16
  #define UPDFROM_14 UPD(14) UPDFROM_15
  #define UPDFROM_13 UPD(13) UPDFROM_14
  #define UPDFROM_12 UPD(12) UPDFROM_13
  #define UPDFROM_11 UPD(11) UPDFROM_12
  #define UPDFROM_10 UPD(10) UPDFROM_11
  #define UPDFROM_9  UPD(9)  UPDFROM_10
  #define UPDFROM_8  UPD(8)  UPDFROM_9
  #define UPDFROM_7  UPD(7)  UPDFROM_8
  #define UPDFROM_6  UPD(6)  UPDFROM_7
  #define UPDFROM_5  UPD(5)  UPDFROM_6
  #define UPDFROM_4  UPD(4)  UPDFROM_5
  #define UPDFROM_3  UPD(3)  UPDFROM_4
  #define UPDFROM_2  UPD(2)  UPDFROM_3
  #define UPDFROM_1  UPD(1)  UPDFROM_2
  #define UPDFROM_0  UPD(0)  UPDFROM_1

  // Step J: L0 = J>>1 (owner's local reg for column J), PAR = J&1 = owner
  // half = LDS slot parity. One barrier per step; slot reuse at J+2 is
  // safe because readers of slot PAR at step J complete before barrier J+1,
  // and the J+2 owner writes only after passing barrier J+1.
  #define STEP(L0, PAR) { \
    if (h == (PAR)) { \
      unsigned key = ((__float_as_uint(q##L0) & 0x7FFFFFC0u) | lu) & aliveq; \
      key = dpp_max64_to_lane63(key); \
      const int pp = __builtin_amdgcn_readlane((int)key, 63) & 63; \
      const unsigned pvb = (unsigned)__builtin_amdgcn_readlane( \
          __float_as_int(q##L0), pp); \
      const float piv = __uint_as_float(pvb); \
      float r0 = __builtin_amdgcn_rcpf(piv); \
      r0 = fmaf(fmaf(-piv, r0, 1.0f), r0, r0); \
      const float rp = ((pvb & 0x7FFFFFFFu) != 0u) ? r0 : 0.0f; \
      const unsigned am = aliveq & ((lane == pp) ? 0u : 0xFFFFFFFFu); \
      const float mv = __uint_as_float(__float_as_uint(q##L0 * rp) & am); \
      mbuf[PAR][dloc][lane] = mv; \
      if (lane == 0) { meta[PAR][dloc][0] = pp; meta[PAR][dloc][1] = (int)pvb; } \
    } \
    __syncthreads(); \
    { \
      const float mult = mbuf[PAR][dloc][lane]; \
      const int   pv0  = meta[PAR][dloc][0]; \
      const int   pv1  = meta[PAR][dloc][1]; \
      const int      p  = __builtin_amdgcn_readfirstlane(pv0); \
      const unsigned pb = (unsigned)__builtin_amdgcn_readfirstlane(pv1); \
      esum += (int)((pb >> 23) & 0xFFu) - 127; \
      sgnx ^= (pb & 0x80000000u); \
      mant_prod *= __uint_as_float((pb & 0x007FFFFFu) | 0x3F800000u); \
      invsum += __popcll(chosen >> (p + 1)); \
      chosen |= 1ull << (unsigned)p; \
      aliveq = (lane == p) ? 0u : aliveq; \
      UPDFROM_##L0 \
    } }

  STEP(0,0)   STEP(0,1)   STEP(1,0)   STEP(1,1)   STEP(2,0)   STEP(2,1)
  STEP(3,0)   STEP(3,1)   STEP(4,0)   STEP(4,1)   STEP(5,0)   STEP(5,1)
  STEP(6,0)   STEP(6,1)   STEP(7,0)   STEP(7,1)   STEP(8,0)   STEP(8,1)
  STEP(9,0)   STEP(9,1)   STEP(10,0)  STEP(10,1)  STEP(11,0)  STEP(11,1)
  STEP(12,0)  STEP(12,1)  STEP(13,0)  STEP(13,1)  STEP(14,0)  STEP(14,1)
  STEP(15,0)  STEP(15,1)  STEP(16,0)  STEP(16,1)  STEP(17,0)  STEP(17,1)
  STEP(18,0)  STEP(18,1)  STEP(19,0)  STEP(19,1)  STEP(20,0)  STEP(20,1)
  STEP(21,0)  STEP(21,1)  STEP(22,0)  STEP(22,1)  STEP(23,0)  STEP(23,1)
  STEP(24,0)  STEP(24,1)
  #undef STEP
  #undef UPD

  const double logdet =
      log((double)mant_prod) + (double)esum * 0.6931471805599453;
  const int sgn = (((sgnx >> 31) + (unsigned)invsum) & 1u) ? -1 : 1;

  if (h == 0 && lane == 0) {
    size_t o = (((size_t)b * 2 + spin) * KDET + k) * 2;
    dets[o]     = logdet;
    dets[o + 1] = (double)sgn;
  }
}

// PLANAR complex64 output: out[0..B) = log_abs (real), out[B..2B) = phase (imag)
__global__ __launch_bounds__(256) void combine_kernel(
    const double* __restrict__ dets, float* __restrict__ out, int B)
{
  int b = blockIdx.x * blockDim.x + threadIdx.x;
  if (b >= B) return;
  const double* du = dets + ((size_t)b * 2 + 0) * KDET * 2;
  const double* dd = dets + ((size_t)b * 2 + 1) * KDET * 2;
  double t[KDET], s[KDET], m = -1e300;
  #pragma unroll
  for (int k = 0; k < KDET; ++k) {
    t[k] = du[2 * k] + dd[2 * k];
    s[k] = du[2 * k + 1] * dd[2 * k + 1];
    if (t[k] > m) m = t[k];
  }
  double sum = 0.0;
  #pragma unroll
  for (int k = 0; k < KDET; ++k) {
    if (t[k] > -1e290) sum += s[k] * exp(t[k] - m);
  }
  double p  = (m > -1e290) ? exp(m) * fabs(sum) : 0.0;
  double la = log(p + 1e-30);                    // reproduce ref clamp exactly
  float phase = (sum >= 0.0) ? 0.0f : 3.14159265358979f;
  out[b]     = (float)la;
  out[B + b] = phase;
}

extern "C" void kernel_launch(void* const* d_in, const int* in_sizes, int n_in,
                              void* d_out, int out_size, void* d_ws, size_t ws_size,
                              hipStream_t stream) {
  const int*   configs = (const int*)  d_in[0];
  const float* tok     = (const float*)d_in[1];
  const float* pos     = (const float*)d_in[2];
  const float* W       = (const float*)d_in[3];
  const float* bv      = (const float*)d_in[4];

  float*  wsf  = (float*)d_ws;
  float*  T    = wsf;                       // 4*400 floats
  float*  P    = wsf + 4 * NTAB;            // 144*400 floats
  double* dets = (double*)(wsf + TP_FLOATS);  // 236800B offset, 8-aligned
  const int B = in_sizes[0] / NSITE;        // total ws: ~499KB

  tp_kernel<<<(148 * NTAB + 255) / 256, 256, 0, stream>>>(tok, pos, W, bv, T, P);
  dim3 grid(B, 2, 2);
  det_kernel<<<grid, 256, 0, stream>>>(configs, T, P, dets);
  combine_kernel<<<(B + 255) / 256, 256, 0, stream>>>(dets, (float*)d_out, B);
}